// Round 1
// baseline (771.217 us; speedup 1.0000x reference)
//
#include <hip/hip_runtime.h>
#include <math.h>

#define NN 768
#define SD 384
#define PD 128
#define DD 16
#define HH 12

__device__ __forceinline__ float wave_max(float v){ for(int o=32;o;o>>=1) v=fmaxf(v,__shfl_xor(v,o)); return v; }
__device__ __forceinline__ float wave_sum(float v){ for(int o=32;o;o>>=1) v+=__shfl_xor(v,o); return v; }

#define W_L 0.57735026918962576f   /* sqrt(1/3) */
#define W_C 0.23570226039551584f   /* sqrt(2/36) */

// ---------------- K1: projections + frames + packed Q~/K~/vv -------------
__global__ __launch_bounds__(256) void k1_prep(
    const float* __restrict__ single, const float* __restrict__ rot,
    const float* __restrict__ trans, const float* __restrict__ Wqkv,
    const float* __restrict__ Wqk, const float* __restrict__ Wvp,
    const float* __restrict__ gamma, float* __restrict__ Qt,
    float* __restrict__ Kt, float* __restrict__ vv)
{
  __shared__ float srow[4][SD];
  __shared__ float raw[4][1152];
  __shared__ float gbuf[4][16][HH][3];
  const int tid = threadIdx.x;
  const int i0 = blockIdx.x * 4;

  for (int s = tid; s < 4*96; s += 256) {
    int r = s / 96, q = s % 96;
    *(float4*)(&srow[r][q*4]) = *(const float4*)(single + (size_t)(i0+r)*SD + q*4);
  }
  __syncthreads();

  for (int c = tid; c < 1152; c += 256) {
    const float* W; int stride, col;
    if (c < 576)      { W = Wqkv; stride = 576; col = c; }
    else if (c < 864) { W = Wqk;  stride = 288; col = c - 576; }
    else              { W = Wvp;  stride = 288; col = c - 864; }
    float a0=0,a1=0,a2=0,a3=0;
    const float* wp = W + col;
    for (int z = 0; z < SD; ++z) {
      float w = wp[(size_t)z*stride];
      a0 += w*srow[0][z]; a1 += w*srow[1][z]; a2 += w*srow[2][z]; a3 += w*srow[3][z];
    }
    raw[0][c]=a0; raw[1][c]=a1; raw[2][c]=a2; raw[3][c]=a3;
  }
  __syncthreads();

  // q/k/v scalar channels
  for (int s = tid; s < 4*576; s += 256) {
    int r = s / 576, cc = s % 576;
    int d = (cc % 192) / HH, h = cc % HH;
    int i = i0 + r;
    float val = raw[r][cc];
    if (cc < 192)       Qt[(size_t)i*384 + h*32 + d] = 0.25f*W_L*val;
    else if (cc < 384)  Kt[(size_t)i*384 + h*32 + d] = val;
    else                vv[(size_t)i*480 + h*40 + d] = val;
  }
  // frames: 4r x 16slot x 12h
  for (int s = tid; s < 768; s += 256) {
    int r = s / 192, rem = s % 192;
    int slot = rem / HH, h = rem % HH;
    int i = i0 + r;
    int base;
    if (slot < 4) base = 576 + slot*36;
    else if (slot < 8) base = 720 + (slot-4)*36;
    else base = 864 + (slot-8)*36;
    float x0 = raw[r][base + 0*12 + h];
    float x1 = raw[r][base + 1*12 + h];
    float x2 = raw[r][base + 2*12 + h];
    const float* R = rot + (size_t)i*9;
    const float* T = trans + (size_t)i*3;
    float g0 = R[0]*x0 + R[1]*x1 + R[2]*x2 + T[0];
    float g1 = R[3]*x0 + R[4]*x1 + R[5]*x2 + T[1];
    float g2 = R[6]*x0 + R[7]*x1 + R[8]*x2 + T[2];
    gbuf[r][slot][h][0]=g0; gbuf[r][slot][h][1]=g1; gbuf[r][slot][h][2]=g2;
    if (slot < 4) {
      float sc2 = 2.0f*W_L*(gamma[h]*W_C*0.5f);
      float* q = Qt + (size_t)i*384 + h*32 + 16 + slot*3;
      q[0]=sc2*g0; q[1]=sc2*g1; q[2]=sc2*g2;
    } else if (slot < 8) {
      float* k = Kt + (size_t)i*384 + h*32 + 16 + (slot-4)*3;
      k[0]=g0; k[1]=g1; k[2]=g2;
    } else {
      float* vp = vv + (size_t)i*480 + h*40 + 16 + (slot-8)*3;
      vp[0]=g0; vp[1]=g1; vp[2]=g2;
    }
  }
  __syncthreads();
  // squared norms -> tail slots
  for (int s = tid; s < 96; s += 256) {
    int r = s / 24, rem = s % 24;
    int h = rem / 2, qk = rem % 2;
    int i = i0 + r;
    float sum = 0;
    int b0 = qk ? 4 : 0;
    for (int p = 0; p < 4; ++p)
      for (int t = 0; t < 3; ++t) { float g = gbuf[r][b0+p][h][t]; sum += g*g; }
    float sc = gamma[h]*W_C*0.5f;
    if (qk == 0) {
      float* q = Qt + (size_t)i*384 + h*32;
      q[28] = -W_L*sc; q[29] = -W_L*sc*sum; q[30] = 0.f; q[31] = 0.f;
    } else {
      float* k = Kt + (size_t)i*384 + h*32;
      k[28] = sum; k[29] = 1.f; k[30] = 0.f; k[31] = 0.f;
    }
  }
}

// ---------------- K2: logits = dot(Q~,K~) + wL * (pair @ Wb) -------------
__global__ __launch_bounds__(256) void k2_logits(
    const float* __restrict__ pair, const float* __restrict__ Wb,
    const float* __restrict__ Qt, const float* __restrict__ Kt,
    float* __restrict__ Lbuf)
{
  __shared__ float pl[64*129];
  __shared__ float wbt[12*129];
  __shared__ float qtl[384];
  const int tid = threadIdx.x;
  const int i  = blockIdx.x / 12;
  const int j0 = (blockIdx.x % 12) * 64;

  for (int s = tid; s < 1536; s += 256) {
    int z = s / 12, h = s % 12;
    wbt[h*129 + z] = Wb[s];
  }
  for (int s = tid; s < 384; s += 256) qtl[s] = Qt[(size_t)i*384 + s];
  const float* src = pair + (size_t)(i*NN + j0)*PD;
  for (int s = tid; s < 2048; s += 256) {
    float4 v = *(const float4*)(src + (size_t)s*4);
    int jj = s >> 5, zq = s & 31;
    float* d = &pl[jj*129 + zq*4];
    d[0]=v.x; d[1]=v.y; d[2]=v.z; d[3]=v.w;
  }
  __syncthreads();

  const int jj = tid & 63;
  const int h0 = (tid >> 6) * 3;
  const int j = j0 + jj;
  float b0=0,b1=0,b2=0;
  const float* prow = &pl[jj*129];
  for (int z = 0; z < 128; ++z) {
    float pv = prow[z];
    b0 += pv * wbt[(h0+0)*129 + z];
    b1 += pv * wbt[(h0+1)*129 + z];
    b2 += pv * wbt[(h0+2)*129 + z];
  }
  float bs[3] = {b0,b1,b2};
  for (int e = 0; e < 3; ++e) {
    int h = h0 + e;
    const float4* kp = (const float4*)(Kt + (size_t)j*384 + h*32);
    const float4* qp = (const float4*)(&qtl[h*32]);
    float dot = 0;
    for (int m = 0; m < 8; ++m) {
      float4 a = qp[m], b = kp[m];
      dot += a.x*b.x + a.y*b.y + a.z*b.z + a.w*b.w;
    }
    Lbuf[((size_t)i*12 + h)*NN + j] = dot + W_L*bs[e];
  }
}

// ---------------- K3: softmax + out_pair contraction ---------------------
__global__ __launch_bounds__(256) void k3_softmax_pair(
    const float* __restrict__ pair, float* __restrict__ Lbuf,
    float* __restrict__ C2)
{
  __shared__ float al[12*768];
  __shared__ float tile[32*132];
  const int tid = threadIdx.x;
  const int i = blockIdx.x;
  float* Lr = Lbuf + (size_t)i*12*NN;
  for (int s = tid; s < 2304; s += 256)
    *(float4*)(&al[s*4]) = *(const float4*)(Lr + (size_t)s*4);
  __syncthreads();

  const int wv = tid >> 6, ln = tid & 63;
  for (int m = 0; m < 3; ++m) {
    int h = wv + 4*m;
    float* row = &al[h*768];
    float mx = -1e30f;
    for (int jj = ln; jj < 768; jj += 64) mx = fmaxf(mx, row[jj]);
    mx = wave_max(mx);
    float sm = 0;
    for (int jj = ln; jj < 768; jj += 64) { float e = __expf(row[jj]-mx); row[jj]=e; sm += e; }
    sm = wave_sum(sm);
    float inv = 1.0f / sm;
    float* rg = Lr + (size_t)h*768;
    for (int jj = ln; jj < 768; jj += 64) { float a = row[jj]*inv; row[jj]=a; rg[jj]=a; }
  }
  __syncthreads();

  float acc[8] = {0,0,0,0,0,0,0,0};
  const int z8 = tid & 15, h = tid >> 4;    // valid when tid < 192
  for (int jt = 0; jt < 24; ++jt) {
    const float* src = pair + ((size_t)i*NN + jt*32)*PD;
    __syncthreads();
    for (int s = tid; s < 1024; s += 256) {
      float4 v = *(const float4*)(src + (size_t)s*4);
      int jj = s >> 5, zq = s & 31;
      *(float4*)(&tile[jj*132 + zq*4]) = v;
    }
    __syncthreads();
    if (tid < 192) {
      const float* arow = &al[h*768 + jt*32];
      for (int jj = 0; jj < 32; ++jj) {
        float av = arow[jj];
        const float4 p0 = *(const float4*)(&tile[jj*132 + z8*8]);
        const float4 p1 = *(const float4*)(&tile[jj*132 + z8*8 + 4]);
        acc[0] += av*p0.x; acc[1] += av*p0.y; acc[2] += av*p0.z; acc[3] += av*p0.w;
        acc[4] += av*p1.x; acc[5] += av*p1.y; acc[6] += av*p1.z; acc[7] += av*p1.w;
      }
    }
  }
  if (tid < 192) {
    float* out = C2 + (size_t)i*2112;
    for (int e = 0; e < 8; ++e) {
      int z = z8*8 + e;
      out[z*12 + h] = acc[e];
    }
  }
}

// ---------------- K4: out_value + points + norms -------------------------
__global__ __launch_bounds__(256) void k4_value_points(
    const float* __restrict__ Lbuf, const float* __restrict__ vvg,
    const float* __restrict__ rot, const float* __restrict__ trans,
    float* __restrict__ C2)
{
  __shared__ float vvl[16*480];
  __shared__ float at[4][12][16];
  __shared__ float outl[4][480];
  const int tid = threadIdx.x;
  const int i0 = blockIdx.x * 4;
  const int h = tid / 20, c0 = tid % 20;   // active if h < 12
  float acc0[4] = {0,0,0,0}, acc1[4] = {0,0,0,0};

  for (int jt = 0; jt < 48; ++jt) {
    __syncthreads();
    const float* src = vvg + (size_t)jt*16*480;
    for (int s = tid; s < 1920; s += 256)
      *(float4*)(&vvl[s*4]) = *(const float4*)(src + (size_t)s*4);
    for (int s = tid; s < 768; s += 256) {
      int r = s / 192, t2 = s % 192, h2 = t2 / 16, jj = t2 & 15;
      at[r][h2][jj] = Lbuf[((size_t)(i0+r)*12 + h2)*768 + jt*16 + jj];
    }
    __syncthreads();
    if (h < 12) {
      for (int jj = 0; jj < 16; ++jj) {
        float v0 = vvl[jj*480 + h*40 + c0];
        float v1 = vvl[jj*480 + h*40 + c0 + 20];
        float a0 = at[0][h][jj], a1 = at[1][h][jj], a2 = at[2][h][jj], a3 = at[3][h][jj];
        acc0[0] += a0*v0; acc0[1] += a1*v0; acc0[2] += a2*v0; acc0[3] += a3*v0;
        acc1[0] += a0*v1; acc1[1] += a1*v1; acc1[2] += a2*v1; acc1[3] += a3*v1;
      }
    }
  }
  __syncthreads();
  if (h < 12) {
    for (int r = 0; r < 4; ++r) {
      outl[r][h*40 + c0] = acc0[r];
      outl[r][h*40 + c0 + 20] = acc1[r];
    }
  }
  __syncthreads();
  for (int s = tid; s < 768; s += 256) {
    int r = s / 192, t2 = s % 192, d = t2 / 12, h2 = t2 % 12;
    C2[(size_t)(i0+r)*2112 + 1536 + d*12 + h2] = outl[r][h2*40 + d];
  }
  for (int s = tid; s < 384; s += 256) {
    int r = s / 96, t2 = s % 96, p = t2 / 12, h2 = t2 % 12;
    int i = i0 + r;
    const float* R = rot + (size_t)i*9;
    const float* T = trans + (size_t)i*3;
    float x0 = outl[r][h2*40 + 16 + p*3 + 0] - T[0];
    float x1 = outl[r][h2*40 + 16 + p*3 + 1] - T[1];
    float x2 = outl[r][h2*40 + 16 + p*3 + 2] - T[2];
    float y0 = R[0]*x0 + R[3]*x1 + R[6]*x2;
    float y1 = R[1]*x0 + R[4]*x1 + R[7]*x2;
    float y2 = R[2]*x0 + R[5]*x1 + R[8]*x2;
    float* o = C2 + (size_t)i*2112;
    o[1728 + p*36 + h2*3 + 0] = y0;
    o[1728 + p*36 + h2*3 + 1] = y1;
    o[1728 + p*36 + h2*3 + 2] = y2;
    o[2016 + p*12 + h2] = sqrtf(y0*y0 + y1*y1 + y2*y2);
  }
}

// ---------------- K5: final GEMM 768x2112 @ 2112x384 + bias --------------
__global__ __launch_bounds__(256) void k5_out(
    const float* __restrict__ C2, const float* __restrict__ Wout,
    const float* __restrict__ bout, float* __restrict__ out)
{
  __shared__ float Al[32*68];
  __shared__ float Bl[64*36];
  const int tid = threadIdx.x;
  const int bm = blockIdx.x / 12, bn = blockIdx.x % 12;
  const int tr = tid / 16, tc = tid % 16;
  float acc00=0, acc01=0, acc10=0, acc11=0;
  for (int kc = 0; kc < 33; ++kc) {
    __syncthreads();
    for (int s = tid; s < 512; s += 256) {
      int row = s / 16, kq = s % 16;
      *(float4*)(&Al[row*68 + kq*4]) =
        *(const float4*)(C2 + (size_t)(bm*32+row)*2112 + kc*64 + kq*4);
    }
    for (int s = tid; s < 512; s += 256) {
      int kk = s / 8, cq = s % 8;
      *(float4*)(&Bl[kk*36 + cq*4]) =
        *(const float4*)(Wout + (size_t)(kc*64+kk)*384 + bn*32 + cq*4);
    }
    __syncthreads();
    for (int kk = 0; kk < 64; ++kk) {
      float a0 = Al[(tr*2)*68 + kk], a1 = Al[(tr*2+1)*68 + kk];
      float b0 = Bl[kk*36 + tc*2], b1 = Bl[kk*36 + tc*2 + 1];
      acc00 += a0*b0; acc01 += a0*b1;
      acc10 += a1*b0; acc11 += a1*b1;
    }
  }
  int r0 = bm*32 + tr*2, c0 = bn*32 + tc*2;
  out[(size_t)r0*384 + c0]       = acc00 + bout[c0];
  out[(size_t)r0*384 + c0+1]     = acc01 + bout[c0+1];
  out[(size_t)(r0+1)*384 + c0]   = acc10 + bout[c0];
  out[(size_t)(r0+1)*384 + c0+1] = acc11 + bout[c0+1];
}

extern "C" void kernel_launch(void* const* d_in, const int* in_sizes, int n_in,
                              void* d_out, int out_size, void* d_ws, size_t ws_size,
                              hipStream_t stream)
{
  const float* single = (const float*)d_in[0];
  const float* pair   = (const float*)d_in[1];
  const float* rot    = (const float*)d_in[2];
  const float* trans  = (const float*)d_in[3];
  const float* Wqkv   = (const float*)d_in[4];
  const float* Wb     = (const float*)d_in[5];
  const float* Wqk    = (const float*)d_in[6];
  const float* Wvp    = (const float*)d_in[7];
  const float* gamma  = (const float*)d_in[8];
  const float* Wout   = (const float*)d_in[9];
  const float* bout   = (const float*)d_in[10];

  float* ws = (float*)d_ws;
  float* Qt = ws;                                  // 768*384
  float* Kt = Qt + (size_t)768*384;                // 768*384
  float* vv = Kt + (size_t)768*384;                // 768*480
  float* Lb = vv + (size_t)768*480;                // 768*12*768
  float* C2 = Lb + (size_t)768*12*768;             // 768*2112
  float* out = (float*)d_out;

  k1_prep<<<dim3(192), dim3(256), 0, stream>>>(single, rot, trans, Wqkv, Wqk, Wvp, gamma, Qt, Kt, vv);
  k2_logits<<<dim3(9216), dim3(256), 0, stream>>>(pair, Wb, Qt, Kt, Lb);
  k3_softmax_pair<<<dim3(768), dim3(256), 0, stream>>>(pair, Lb, C2);
  k4_value_points<<<dim3(192), dim3(256), 0, stream>>>(Lb, vv, rot, trans, C2);
  k5_out<<<dim3(288), dim3(256), 0, stream>>>(C2, Wout, bout, out);
}

// Round 2
// 329.881 us; speedup vs baseline: 2.3379x; 2.3379x over previous
//
#include <hip/hip_runtime.h>
#include <math.h>

#define NN 768
#define SD 384
#define HH 12

#define W_L 0.57735026918962576f   /* sqrt(1/3) */
#define W_C 0.23570226039551584f   /* sqrt(2/36) */

__device__ __forceinline__ float dot32(const float* q, const float* k) {
  float s = 0.f;
  #pragma unroll
  for (int m = 0; m < 8; ++m) {
    float4 a = *(const float4*)(q + m*4);
    float4 b = *(const float4*)(k + m*4);
    s += a.x*b.x + a.y*b.y + a.z*b.z + a.w*b.w;
  }
  return s;
}

// ---------------- K1a: raw = single @ [Wqkv|Wqk|Wvp]  (768x1152x384) ----
__global__ __launch_bounds__(256) void k1a_gemm(
    const float* __restrict__ single, const float* __restrict__ Wqkv,
    const float* __restrict__ Wqk, const float* __restrict__ Wvp,
    float* __restrict__ raw)
{
  __shared__ float Al[64][17];
  __shared__ float Bl[16][68];
  const int tid = threadIdx.x;
  const int bm = blockIdx.x / 18, bn = blockIdx.x % 18;
  const int tr = tid >> 4, tc = tid & 15;

  const int bcol = bn*64 + (tid & 15)*4;
  const float* Wsrc; int wstride;
  if (bcol < 576)      { Wsrc = Wqkv + bcol;        wstride = 576; }
  else if (bcol < 864) { Wsrc = Wqk  + (bcol-576);  wstride = 288; }
  else                 { Wsrc = Wvp  + (bcol-864);  wstride = 288; }
  const int brow = tid >> 4;
  const int ar = tid >> 2, ac = (tid & 3)*4;

  float4 acc0 = {0,0,0,0}, acc1 = {0,0,0,0}, acc2 = {0,0,0,0}, acc3 = {0,0,0,0};

  for (int kc = 0; kc < 24; ++kc) {
    __syncthreads();
    *(float4*)&Al[ar][ac] = *(const float4*)(single + (size_t)(bm*64+ar)*SD + kc*16 + ac);
    *(float4*)&Bl[brow][(tid&15)*4] = *(const float4*)(Wsrc + (size_t)(kc*16+brow)*wstride);
    __syncthreads();
    #pragma unroll
    for (int kk = 0; kk < 16; ++kk) {
      float a0 = Al[tr*4+0][kk], a1 = Al[tr*4+1][kk], a2 = Al[tr*4+2][kk], a3 = Al[tr*4+3][kk];
      float4 bv = *(float4*)&Bl[kk][tc*4];
      acc0.x += a0*bv.x; acc0.y += a0*bv.y; acc0.z += a0*bv.z; acc0.w += a0*bv.w;
      acc1.x += a1*bv.x; acc1.y += a1*bv.y; acc1.z += a1*bv.z; acc1.w += a1*bv.w;
      acc2.x += a2*bv.x; acc2.y += a2*bv.y; acc2.z += a2*bv.z; acc2.w += a2*bv.w;
      acc3.x += a3*bv.x; acc3.y += a3*bv.y; acc3.z += a3*bv.z; acc3.w += a3*bv.w;
    }
  }
  float* o = raw + (size_t)(bm*64 + tr*4)*1152 + bn*64 + tc*4;
  *(float4*)(o)            = acc0;
  *(float4*)(o + 1152)     = acc1;
  *(float4*)(o + 2*1152)   = acc2;
  *(float4*)(o + 3*1152)   = acc3;
}

// ---------------- K1b: pack Q~/K~/vv + frames ---------------------------
__global__ __launch_bounds__(256) void k1b_pack(
    const float* __restrict__ raw_g, const float* __restrict__ rot,
    const float* __restrict__ trans, const float* __restrict__ gamma,
    float* __restrict__ Qt, float* __restrict__ Kt, float* __restrict__ vv)
{
  __shared__ float raw[4][1152];
  __shared__ float gbuf[4][16][HH][3];
  const int tid = threadIdx.x;
  const int i0 = blockIdx.x * 4;

  for (int s = tid; s < 4*288; s += 256) {
    int r = s / 288, q = s % 288;
    *(float4*)(&raw[r][q*4]) = *(const float4*)(raw_g + (size_t)(i0+r)*1152 + q*4);
  }
  __syncthreads();

  for (int s = tid; s < 4*576; s += 256) {
    int r = s / 576, cc = s % 576;
    int d = (cc % 192) / HH, h = cc % HH;
    int i = i0 + r;
    float val = raw[r][cc];
    if (cc < 192)       Qt[(size_t)i*384 + h*32 + d] = 0.25f*W_L*val;
    else if (cc < 384)  Kt[(size_t)i*384 + h*32 + d] = val;
    else                vv[(size_t)i*480 + h*40 + d] = val;
  }
  for (int s = tid; s < 768; s += 256) {
    int r = s / 192, rem = s % 192;
    int slot = rem / HH, h = rem % HH;
    int i = i0 + r;
    int base;
    if (slot < 4) base = 576 + slot*36;
    else if (slot < 8) base = 720 + (slot-4)*36;
    else base = 864 + (slot-8)*36;
    float x0 = raw[r][base + 0*12 + h];
    float x1 = raw[r][base + 1*12 + h];
    float x2 = raw[r][base + 2*12 + h];
    const float* R = rot + (size_t)i*9;
    const float* T = trans + (size_t)i*3;
    float g0 = R[0]*x0 + R[1]*x1 + R[2]*x2 + T[0];
    float g1 = R[3]*x0 + R[4]*x1 + R[5]*x2 + T[1];
    float g2 = R[6]*x0 + R[7]*x1 + R[8]*x2 + T[2];
    gbuf[r][slot][h][0]=g0; gbuf[r][slot][h][1]=g1; gbuf[r][slot][h][2]=g2;
    if (slot < 4) {
      float sc2 = 2.0f*W_L*(gamma[h]*W_C*0.5f);
      float* q = Qt + (size_t)i*384 + h*32 + 16 + slot*3;
      q[0]=sc2*g0; q[1]=sc2*g1; q[2]=sc2*g2;
    } else if (slot < 8) {
      float* k = Kt + (size_t)i*384 + h*32 + 16 + (slot-4)*3;
      k[0]=g0; k[1]=g1; k[2]=g2;
    } else {
      float* vp = vv + (size_t)i*480 + h*40 + 16 + (slot-8)*3;
      vp[0]=g0; vp[1]=g1; vp[2]=g2;
    }
  }
  __syncthreads();
  for (int s = tid; s < 96; s += 256) {
    int r = s / 24, rem = s % 24;
    int h = rem / 2, qk = rem % 2;
    int i = i0 + r;
    float sum = 0;
    int b0 = qk ? 4 : 0;
    for (int p = 0; p < 4; ++p)
      for (int t = 0; t < 3; ++t) { float g = gbuf[r][b0+p][h][t]; sum += g*g; }
    float sc = gamma[h]*W_C*0.5f;
    if (qk == 0) {
      float* q = Qt + (size_t)i*384 + h*32;
      q[28] = -W_L*sc; q[29] = -W_L*sc*sum; q[30] = 0.f; q[31] = 0.f;
    } else {
      float* k = Kt + (size_t)i*384 + h*32;
      k[28] = sum; k[29] = 1.f; k[30] = 0.f; k[31] = 0.f;
    }
  }
}

// ---------------- K2f: fused logits+softmax+all contractions ------------
__global__ __launch_bounds__(256, 4) void k2f(
    const float* __restrict__ pair, const float* __restrict__ Wb,
    const float* __restrict__ Qt, const float* __restrict__ Kt,
    const float* __restrict__ vv, const float* __restrict__ rot,
    const float* __restrict__ trans, float* __restrict__ C2)
{
  __shared__ float Wl[1536];
  __shared__ float Qrow[384];
  __shared__ float Ta[32*68];
  __shared__ float Tb[32*68];
  __shared__ float part[4*12*33];
  __shared__ float plds[12*33];
  __shared__ float scl[12];
  __shared__ float smm[12], sms[12];
  __shared__ float oacc[480];

  const int tid = threadIdx.x;
  const int i = blockIdx.x;
  const int wave = tid >> 6;
  const int lane = tid & 63;
  const int jj = lane & 31;
  const int half = lane >> 5;

  for (int s = tid; s < 1536; s += 256) Wl[s] = Wb[s];
  for (int s = tid; s < 384; s += 256) Qrow[s] = Qt[(size_t)i*384 + s];
  if (tid < 12) { smm[tid] = -1e30f; sms[tid] = 0.f; }
  __syncthreads();

  const int zbase = wave*32 + half*16;
  const float* prow = pair + (size_t)i*NN*128;

  // role A constants (tid < 192): z4 in 0..31, hgA in 0..5
  const int z4 = tid & 31, hgA = tid >> 5;
  float* TbaseA = ((z4 & 1) ? Tb : Ta) + ((z4 >> 1) * 4);
  // role B constants (tid 192..251)
  const int lB = tid - 192;
  const int hB = (lB < 60 && lB >= 0) ? lB / 5 : 0;
  const int cgB = hB*40 + (((lB >= 0 ? lB : 0) % 5) * 8);

  float4 ra[4], rb[4];
  float accA[2][4] = {{0,0,0,0},{0,0,0,0}};
  float accB[8] = {0,0,0,0,0,0,0,0};

  // load tile 0
  {
    const float* src = prow + (size_t)jj*128 + zbase;
    ra[0] = *(const float4*)(src);
    ra[1] = *(const float4*)(src + 4);
    ra[2] = *(const float4*)(src + 8);
    ra[3] = *(const float4*)(src + 12);
  }

  auto iter = [&](int t, float4 (&cur)[4], float4 (&nxt)[4]) {
    const int j0 = t*32;
    // A: prefetch next tile
    if (t < 23) {
      const float* src = prow + (size_t)(j0 + 32 + jj)*128 + zbase;
      nxt[0] = *(const float4*)(src);
      nxt[1] = *(const float4*)(src + 4);
      nxt[2] = *(const float4*)(src + 8);
      nxt[3] = *(const float4*)(src + 12);
    }
    // B: stage T to LDS + b-partials from regs
    #pragma unroll
    for (int k = 0; k < 4; ++k) {
      const int z4w = wave*8 + half*4 + k;
      float* dst = ((z4w & 1) ? Tb : Ta) + jj*68 + (z4w >> 1)*4;
      *(float4*)dst = cur[k];
    }
    {
      float4 pb0 = {0,0,0,0}, pb1 = {0,0,0,0}, pb2 = {0,0,0,0};
      #pragma unroll
      for (int k = 0; k < 4; ++k) {
        #pragma unroll
        for (int e = 0; e < 4; ++e) {
          const float tv = (e==0) ? cur[k].x : (e==1) ? cur[k].y : (e==2) ? cur[k].z : cur[k].w;
          const float* w = &Wl[(zbase + k*4 + e)*12];
          float4 w0 = *(const float4*)(w);
          float4 w1 = *(const float4*)(w + 4);
          float4 w2 = *(const float4*)(w + 8);
          pb0.x += tv*w0.x; pb0.y += tv*w0.y; pb0.z += tv*w0.z; pb0.w += tv*w0.w;
          pb1.x += tv*w1.x; pb1.y += tv*w1.y; pb1.z += tv*w1.z; pb1.w += tv*w1.w;
          pb2.x += tv*w2.x; pb2.y += tv*w2.y; pb2.z += tv*w2.z; pb2.w += tv*w2.w;
        }
      }
      pb0.x += __shfl_xor(pb0.x, 32); pb0.y += __shfl_xor(pb0.y, 32);
      pb0.z += __shfl_xor(pb0.z, 32); pb0.w += __shfl_xor(pb0.w, 32);
      pb1.x += __shfl_xor(pb1.x, 32); pb1.y += __shfl_xor(pb1.y, 32);
      pb1.z += __shfl_xor(pb1.z, 32); pb1.w += __shfl_xor(pb1.w, 32);
      pb2.x += __shfl_xor(pb2.x, 32); pb2.y += __shfl_xor(pb2.y, 32);
      pb2.z += __shfl_xor(pb2.z, 32); pb2.w += __shfl_xor(pb2.w, 32);
      if (half == 0) {
        float* pp = part + (wave*12)*33 + jj;
        pp[0*33] = pb0.x; pp[1*33] = pb0.y; pp[2*33] = pb0.z; pp[3*33] = pb0.w;
        pp[4*33] = pb1.x; pp[5*33] = pb1.y; pp[6*33] = pb1.z; pp[7*33] = pb1.w;
        pp[8*33] = pb2.x; pp[9*33] = pb2.y; pp[10*33] = pb2.z; pp[11*33] = pb2.w;
      }
    }
    __syncthreads();   // B1
    // C: dot-logits + combine with b
    {
      const int hg = tid >> 5, jc = tid & 31;
      const float* kr = Kt + (size_t)(j0 + jc)*384;
      {
        float d = dot32(&Qrow[hg*32], kr + hg*32);
        const float* pp = part + hg*33 + jc;
        float bs = pp[0] + pp[396] + pp[792] + pp[1188];
        plds[hg*33 + jc] = d + W_L*bs;
      }
      if (hg < 4) {
        const int h2 = hg + 8;
        float d = dot32(&Qrow[h2*32], kr + h2*32);
        const float* pp = part + h2*33 + jc;
        float bs = pp[0] + pp[396] + pp[792] + pp[1188];
        plds[h2*33 + jc] = d + W_L*bs;
      }
    }
    __syncthreads();   // C1
    // D: online softmax bookkeeping (wave 0, lanes 0..47)
    if (tid < 48) {
      const int h = tid >> 2, q = tid & 3;
      float v0 = plds[h*33 + q*8 + 0], v1 = plds[h*33 + q*8 + 1];
      float v2 = plds[h*33 + q*8 + 2], v3 = plds[h*33 + q*8 + 3];
      float v4 = plds[h*33 + q*8 + 4], v5 = plds[h*33 + q*8 + 5];
      float v6 = plds[h*33 + q*8 + 6], v7 = plds[h*33 + q*8 + 7];
      float mt = fmaxf(fmaxf(fmaxf(v0,v1),fmaxf(v2,v3)), fmaxf(fmaxf(v4,v5),fmaxf(v6,v7)));
      mt = fmaxf(mt, __shfl_xor(mt, 1));
      mt = fmaxf(mt, __shfl_xor(mt, 2));
      float mo = smm[h];
      float mn = fmaxf(mo, mt);
      float sc = __expf(mo - mn);
      float p0 = __expf(v0-mn), p1 = __expf(v1-mn), p2 = __expf(v2-mn), p3 = __expf(v3-mn);
      float p4 = __expf(v4-mn), p5 = __expf(v5-mn), p6 = __expf(v6-mn), p7 = __expf(v7-mn);
      plds[h*33 + q*8 + 0] = p0; plds[h*33 + q*8 + 1] = p1;
      plds[h*33 + q*8 + 2] = p2; plds[h*33 + q*8 + 3] = p3;
      plds[h*33 + q*8 + 4] = p4; plds[h*33 + q*8 + 5] = p5;
      plds[h*33 + q*8 + 6] = p6; plds[h*33 + q*8 + 7] = p7;
      float ps = ((p0+p1)+(p2+p3)) + ((p4+p5)+(p6+p7));
      ps += __shfl_xor(ps, 1);
      ps += __shfl_xor(ps, 2);
      if (q == 0) { sms[h] = sms[h]*sc + ps; smm[h] = mn; scl[h] = sc; }
    }
    __syncthreads();   // D1
    // E: accumulate
    if (tid < 192) {
      const int h0 = hgA*2;
      const float s0 = scl[h0], s1 = scl[h0+1];
      accA[0][0]*=s0; accA[0][1]*=s0; accA[0][2]*=s0; accA[0][3]*=s0;
      accA[1][0]*=s1; accA[1][1]*=s1; accA[1][2]*=s1; accA[1][3]*=s1;
      const float* p0p = &plds[h0*33];
      const float* p1p = &plds[(h0+1)*33];
      #pragma unroll 4
      for (int j2 = 0; j2 < 32; ++j2) {
        float4 tv = *(const float4*)(TbaseA + (size_t)j2*68);
        float p0 = p0p[j2], p1 = p1p[j2];
        accA[0][0] += p0*tv.x; accA[0][1] += p0*tv.y; accA[0][2] += p0*tv.z; accA[0][3] += p0*tv.w;
        accA[1][0] += p1*tv.x; accA[1][1] += p1*tv.y; accA[1][2] += p1*tv.z; accA[1][3] += p1*tv.w;
      }
    } else if (lB < 60) {
      const float sc = scl[hB];
      #pragma unroll
      for (int e = 0; e < 8; ++e) accB[e] *= sc;
      const float* pp = &plds[hB*33];
      const float* vp = vv + (size_t)j0*480 + cgB;
      #pragma unroll 4
      for (int j2 = 0; j2 < 32; ++j2) {
        float4 v0 = *(const float4*)(vp + (size_t)j2*480);
        float4 v1 = *(const float4*)(vp + (size_t)j2*480 + 4);
        float p = pp[j2];
        accB[0] += p*v0.x; accB[1] += p*v0.y; accB[2] += p*v0.z; accB[3] += p*v0.w;
        accB[4] += p*v1.x; accB[5] += p*v1.y; accB[6] += p*v1.z; accB[7] += p*v1.w;
      }
    }
    __syncthreads();   // E1
  };

  #pragma unroll 1
  for (int t2 = 0; t2 < 12; ++t2) {
    iter(2*t2,     ra, rb);
    iter(2*t2 + 1, rb, ra);
  }

  // epilogue
  if (tid < 192) {
    const int h0 = hgA*2;
    const float i0v = 1.0f/sms[h0], i1v = 1.0f/sms[h0+1];
    float* o = C2 + (size_t)i*2112;
    #pragma unroll
    for (int e = 0; e < 4; ++e) {
      o[(z4*4+e)*12 + h0]   = accA[0][e]*i0v;
      o[(z4*4+e)*12 + h0+1] = accA[1][e]*i1v;
    }
  } else if (lB < 60) {
    const float inv = 1.0f/sms[hB];
    #pragma unroll
    for (int e = 0; e < 8; ++e) oacc[cgB+e] = accB[e]*inv;
  }
  __syncthreads();
  if (tid < 96) {
    const int pp = tid / 12, h = tid % 12;
    const float* R = rot + (size_t)i*9;
    const float* T = trans + (size_t)i*3;
    float x0 = oacc[h*40+16+pp*3+0] - T[0];
    float x1 = oacc[h*40+16+pp*3+1] - T[1];
    float x2 = oacc[h*40+16+pp*3+2] - T[2];
    float y0 = R[0]*x0 + R[3]*x1 + R[6]*x2;
    float y1 = R[1]*x0 + R[4]*x1 + R[7]*x2;
    float y2 = R[2]*x0 + R[5]*x1 + R[8]*x2;
    float* o = C2 + (size_t)i*2112;
    o[1728 + pp*36 + h*3 + 0] = y0;
    o[1728 + pp*36 + h*3 + 1] = y1;
    o[1728 + pp*36 + h*3 + 2] = y2;
    o[2016 + pp*12 + h] = sqrtf(y0*y0 + y1*y1 + y2*y2);
  } else if (tid < 192) {
    const int c = tid - 96;
    float* o = C2 + (size_t)i*2112 + 1536;
    o[c]      = oacc[(c%12)*40 + (c/12)];
    o[c+96]   = oacc[((c+96)%12)*40 + ((c+96)/12)];
  }
}

// ---------------- K5: final GEMM 768x2112 @ 2112x384 + bias -------------
__global__ __launch_bounds__(256) void k5_out(
    const float* __restrict__ C2, const float* __restrict__ Wout,
    const float* __restrict__ bout, float* __restrict__ out)
{
  __shared__ float Al[32*68];
  __shared__ float Bl[64*36];
  const int tid = threadIdx.x;
  const int bm = blockIdx.x / 12, bn = blockIdx.x % 12;
  const int tr = tid / 16, tc = tid % 16;
  float acc00=0, acc01=0, acc10=0, acc11=0;
  for (int kc = 0; kc < 33; ++kc) {
    __syncthreads();
    for (int s = tid; s < 512; s += 256) {
      int row = s / 16, kq = s % 16;
      *(float4*)(&Al[row*68 + kq*4]) =
        *(const float4*)(C2 + (size_t)(bm*32+row)*2112 + kc*64 + kq*4);
    }
    for (int s = tid; s < 512; s += 256) {
      int kk = s / 8, cq = s % 8;
      *(float4*)(&Bl[kk*36 + cq*4]) =
        *(const float4*)(Wout + (size_t)(kc*64+kk)*384 + bn*32 + cq*4);
    }
    __syncthreads();
    for (int kk = 0; kk < 64; ++kk) {
      float a0 = Al[(tr*2)*68 + kk], a1 = Al[(tr*2+1)*68 + kk];
      float b0 = Bl[kk*36 + tc*2], b1 = Bl[kk*36 + tc*2 + 1];
      acc00 += a0*b0; acc01 += a0*b1;
      acc10 += a1*b0; acc11 += a1*b1;
    }
  }
  int r0 = bm*32 + tr*2, c0 = bn*32 + tc*2;
  out[(size_t)r0*384 + c0]       = acc00 + bout[c0];
  out[(size_t)r0*384 + c0+1]     = acc01 + bout[c0+1];
  out[(size_t)(r0+1)*384 + c0]   = acc10 + bout[c0];
  out[(size_t)(r0+1)*384 + c0+1] = acc11 + bout[c0+1];
}

extern "C" void kernel_launch(void* const* d_in, const int* in_sizes, int n_in,
                              void* d_out, int out_size, void* d_ws, size_t ws_size,
                              hipStream_t stream)
{
  const float* single = (const float*)d_in[0];
  const float* pair   = (const float*)d_in[1];
  const float* rot    = (const float*)d_in[2];
  const float* trans  = (const float*)d_in[3];
  const float* Wqkv   = (const float*)d_in[4];
  const float* Wb     = (const float*)d_in[5];
  const float* Wqk    = (const float*)d_in[6];
  const float* Wvp    = (const float*)d_in[7];
  const float* gamma  = (const float*)d_in[8];
  const float* Wout   = (const float*)d_in[9];
  const float* bout   = (const float*)d_in[10];

  float* ws  = (float*)d_ws;
  float* raw = ws;                                  // 768*1152
  float* Qt  = raw + (size_t)768*1152;              // 768*384
  float* Kt  = Qt + (size_t)768*384;                // 768*384
  float* vv  = Kt + (size_t)768*384;                // 768*480
  float* C2  = vv + (size_t)768*480;                // 768*2112
  float* out = (float*)d_out;

  k1a_gemm<<<dim3(216), dim3(256), 0, stream>>>(single, Wqkv, Wqk, Wvp, raw);
  k1b_pack<<<dim3(192), dim3(256), 0, stream>>>(raw, rot, trans, gamma, Qt, Kt, vv);
  k2f<<<dim3(768), dim3(256), 0, stream>>>(pair, Wb, Qt, Kt, vv, rot, trans, C2);
  k5_out<<<dim3(288), dim3(256), 0, stream>>>(C2, Wout, bout, out);
}